// Round 5
// baseline (529.051 us; speedup 1.0000x reference)
//
#include <hip/hip_runtime.h>
#include <hip/hip_bf16.h>
#include <math.h>

// ---------------------------------------------------------------------------
// GCN forward: out = log_softmax( A@( relu(A@(x@W1)+b1) @ W2 ) + b2 )
// Round 9 = Round 8 with compile fix: __builtin_nontemporal_load/store need
// scalar or ext_vector types, not HIP_vector_type (float4). Use ext_vector
// f32x4e for those two sites.
// Round 8 summary: spmm1 is fetch-bound at 3.75 TB/s (two structures, same
// 105 us) - leave its loop alone. Instead: (a) fuse gemm2 into spmm1's
// epilogue via LDS (h never touches global: -51 MB round trip, -1 dispatch),
// (b) merge the 3 prep kernels into one dispatch, (c) nontemporal hints on
// stream-once data (col/val/x/out) so they stop evicting gather rows from L2.
// ---------------------------------------------------------------------------

#define GCN_NFEAT 256
#define GCN_NHID  128
#define GCN_NCLASS 40
#define SUP2_LD   64          // padded sup2 row (bf16 elems) = 128 B

typedef __bf16 bf16_t;
typedef bf16_t bf16x8 __attribute__((ext_vector_type(8)));
typedef float  f32x4  __attribute__((ext_vector_type(4)));
typedef float  f32x4e __attribute__((ext_vector_type(4)));  // for nontemporal

static __device__ __forceinline__ unsigned short f2b(float f) {
    bf16_t b = (bf16_t)f;
    return *(unsigned short*)&b;
}
static __device__ __forceinline__ float blo(unsigned int u) {
    return __uint_as_float(u << 16);
}
static __device__ __forceinline__ float bhi(unsigned int u) {
    return __uint_as_float(u & 0xffff0000u);
}

// ---- merged prep: row_ptr + W1t + W2t in one dispatch ----------------------
__global__ __launch_bounds__(256) void k_prep(
    const int* __restrict__ row, int* __restrict__ row_ptr,
    const float* __restrict__ w1, bf16_t* __restrict__ w1t,
    const float* __restrict__ w2, bf16_t* __restrict__ w2t,
    int n_rows, int n_edges, int rb)
{
    const int b = blockIdx.x;
    if (b < rb) {
        // row_ptr[r] = lower_bound(adj_row, r)
        int r = b * 256 + threadIdx.x;
        if (r > n_rows) return;
        int lo = 0, hi = n_edges;
        while (lo < hi) {
            int mid = (lo + hi) >> 1;
            if (row[mid] < r) lo = mid + 1; else hi = mid;
        }
        row_ptr[r] = lo;
    } else if (b < rb + 128) {
        // W1t[128][256]
        int idx = (b - rb) * 256 + threadIdx.x;   // 32768 total
        int c = idx & 127;
        int k = idx >> 7;
        w1t[(size_t)c * GCN_NFEAT + k] = (bf16_t)w1[(size_t)k * GCN_NHID + c];
    } else {
        // W2t[48][128], cols 40..47 zero
        int idx = (b - rb - 128) * 256 + threadIdx.x;  // 6144 total
        if (idx >= 48 * GCN_NHID) return;
        int c = idx / GCN_NHID;
        int k = idx - c * GCN_NHID;
        float v = (c < GCN_NCLASS) ? w2[(size_t)k * GCN_NCLASS + c] : 0.f;
        w2t[idx] = (bf16_t)v;
    }
}

// ---- GEMM1 (MFMA): sup1_bf16[N,128] = bf16( x[N,256] @ W1 ) ----------------
__global__ __launch_bounds__(256) void k_gemm1(
    const float* __restrict__ x, const bf16_t* __restrict__ w1t,
    bf16_t* __restrict__ out, int nrows)
{
    __shared__ __align__(16) bf16_t As[128][72];   // [row][k]
    __shared__ __align__(16) bf16_t Bs[128][72];   // [col][k]

    const int tid  = threadIdx.x;
    const int wave = tid >> 6, lane = tid & 63;
    const int wm = wave >> 1, wn = wave & 1;
    const int lm = lane & 15, quad = lane >> 4;
    const int r0 = blockIdx.x * 128;

    f32x4 acc[4][4] = {};

    for (int k0 = 0; k0 < GCN_NFEAT; k0 += 64) {
        {
            const int row = tid >> 1, half = tid & 1;
            const int gr = r0 + row;
            union { bf16_t b[32]; uint4 q[4]; } t;
            if (gr < nrows) {
                const f32x4e* p = (const f32x4e*)(x + (size_t)gr * GCN_NFEAT + k0 + half * 32);
#pragma unroll
                for (int i = 0; i < 8; i++) {
                    f32x4e v = __builtin_nontemporal_load(p + i);
                    t.b[i*4+0] = (bf16_t)v.x; t.b[i*4+1] = (bf16_t)v.y;
                    t.b[i*4+2] = (bf16_t)v.z; t.b[i*4+3] = (bf16_t)v.w;
                }
            } else {
#pragma unroll
                for (int i = 0; i < 4; i++) t.q[i] = make_uint4(0,0,0,0);
            }
            uint4* dst = (uint4*)&As[row][half * 32];
#pragma unroll
            for (int i = 0; i < 4; i++) dst[i] = t.q[i];
        }
        {
            const int colc = tid >> 1, half = tid & 1;
            const uint4* src = (const uint4*)(w1t + (size_t)colc * GCN_NFEAT + k0 + half * 32);
            uint4* dst = (uint4*)&Bs[colc][half * 32];
#pragma unroll
            for (int i = 0; i < 4; i++) dst[i] = src[i];
        }
        __syncthreads();

#pragma unroll
        for (int ks = 0; ks < 2; ks++) {
            bf16x8 af[4], bfr[4];
#pragma unroll
            for (int i = 0; i < 4; i++)
                af[i] = *(const bf16x8*)&As[wm*64 + i*16 + lm][ks*32 + quad*8];
#pragma unroll
            for (int j = 0; j < 4; j++)
                bfr[j] = *(const bf16x8*)&Bs[wn*64 + j*16 + lm][ks*32 + quad*8];
#pragma unroll
            for (int i = 0; i < 4; i++)
#pragma unroll
                for (int j = 0; j < 4; j++)
                    acc[i][j] = __builtin_amdgcn_mfma_f32_16x16x32_bf16(
                        af[i], bfr[j], acc[i][j], 0, 0, 0);
        }
        __syncthreads();
    }

#pragma unroll
    for (int i = 0; i < 4; i++) {
#pragma unroll
        for (int reg = 0; reg < 4; reg++) {
            const int gr = r0 + wm*64 + i*16 + quad*4 + reg;
            if (gr < nrows) {
#pragma unroll
                for (int j = 0; j < 4; j++) {
                    const int gc = wn*64 + j*16 + lm;
                    out[(size_t)gr * GCN_NHID + gc] = (bf16_t)acc[i][j][reg];
                }
            }
        }
    }
}

// ---- fused spmm1 + gemm2: sup2[N,64pad] = bf16( relu(A@sup1+b1) @ W2 ) -----
// Block = 128 rows. Phase 1 (spmm): each wave serially does 32 rows with the
// R7 quarter-gather loop, packing relu'd h rows into LDS As (never global).
// Phase 2 (gemm2 core): barrier, then the proven 24-MFMA tile on As x Bs(W2t),
// writing 128 B padded sup2 rows. Pad cols 40..47 are real zeros (W2t pad).
#define S1_FENCE(U) asm volatile("" : "+v"(U.x), "+v"(U.y), "+v"(U.z), "+v"(U.w));
#define S1_FMA(U, V)                                   \
    a0 = fmaf(V, blo(U.x), a0); a1 = fmaf(V, bhi(U.x), a1); \
    a2 = fmaf(V, blo(U.y), a2); a3 = fmaf(V, bhi(U.y), a3); \
    a4 = fmaf(V, blo(U.z), a4); a5 = fmaf(V, bhi(U.z), a5); \
    a6 = fmaf(V, blo(U.w), a6); a7 = fmaf(V, bhi(U.w), a7);

__global__ __launch_bounds__(256) void k_spmm1_g2(
    const int* __restrict__ row_ptr, const int* __restrict__ col,
    const float* __restrict__ val, const bf16_t* __restrict__ sup,
    const float* __restrict__ b1, const bf16_t* __restrict__ w2t,
    bf16_t* __restrict__ out, int nrows)
{
    __shared__ __align__(16) bf16_t As[128][136];  // h rows [row][k]
    __shared__ __align__(16) bf16_t Bs[48][136];   // W2t [class][k]

    const int tid  = threadIdx.x;
    const int wave = tid >> 6, lane = tid & 63;
    const int q = lane >> 4;            // quarter: which edge of a group
    const int f = lane & 15;            // feature block 8f..8f+7
    const int r0 = blockIdx.x * 128;
    const char* supb = (const char*)sup;
    const int fo = f * 16;              // byte offset within 256 B sup1 row

    // stage Bs (W2t) while phase 1 runs
    for (int idx = tid; idx < 48 * 16; idx += 256) {
        const int c = idx >> 4, seg = idx & 15;
        ((uint4*)&Bs[c][0])[seg] = ((const uint4*)(w2t + (size_t)c * GCN_NHID))[seg];
    }

    // per-lane bias slice (fixed per lane, hoisted out of the row loop)
    const float4 ba = *(const float4*)(b1 + f * 8);
    const float4 bc = *(const float4*)(b1 + f * 8 + 4);

    // ---- phase 1: 32 rows per wave, quarter-gather spmm ----
    int e1next = -1;
    for (int i = 0; i < 32; i++) {
        const int r = r0 + wave * 32 + i;
        if (r >= nrows) break;
        const int e0 = (e1next >= 0) ? e1next
                                     : __builtin_amdgcn_readfirstlane(row_ptr[r]);
        const int e1 = __builtin_amdgcn_readfirstlane(row_ptr[r + 1]);
        e1next = e1;
        const int n = e1 - e0;

        float a0=0.f,a1=0.f,a2=0.f,a3=0.f,a4=0.f,a5=0.f,a6=0.f,a7=0.f;

        int base = 0;
        for (; base + 16 <= n; base += 16) {
            const int i0 = e0 + base + q;
            const int   c0 = __builtin_nontemporal_load(col + i0);
            const float v0 = __builtin_nontemporal_load(val + i0);
            const int   c1 = __builtin_nontemporal_load(col + i0 + 4);
            const float v1 = __builtin_nontemporal_load(val + i0 + 4);
            const int   c2 = __builtin_nontemporal_load(col + i0 + 8);
            const float v2 = __builtin_nontemporal_load(val + i0 + 8);
            const int   c3 = __builtin_nontemporal_load(col + i0 + 12);
            const float v3 = __builtin_nontemporal_load(val + i0 + 12);
            uint4 u0 = *(const uint4*)(supb + (((size_t)(unsigned)c0) << 8) + fo);
            uint4 u1 = *(const uint4*)(supb + (((size_t)(unsigned)c1) << 8) + fo);
            uint4 u2 = *(const uint4*)(supb + (((size_t)(unsigned)c2) << 8) + fo);
            uint4 u3 = *(const uint4*)(supb + (((size_t)(unsigned)c3) << 8) + fo);
            S1_FENCE(u0) S1_FMA(u0, v0)
            S1_FENCE(u1) S1_FMA(u1, v1)
            S1_FENCE(u2) S1_FMA(u2, v2)
            S1_FENCE(u3) S1_FMA(u3, v3)
        }
        const int rem = n - base;
        if (rem > 0) {
            const int elast = e1 - 1;
            uint4 t0, t1, t2, t3;
            float w0 = 0.f, w1 = 0.f, w2 = 0.f, w3 = 0.f;
            {
                int gi = e0 + base + q; if (gi > elast) gi = elast;
                const int c = col[gi]; w0 = (q < rem) ? val[gi] : 0.f;
                t0 = *(const uint4*)(supb + (((size_t)(unsigned)c) << 8) + fo);
            }
            if (rem > 4) {
                int gi = e0 + base + 4 + q; if (gi > elast) gi = elast;
                const int c = col[gi]; w1 = (4 + q < rem) ? val[gi] : 0.f;
                t1 = *(const uint4*)(supb + (((size_t)(unsigned)c) << 8) + fo);
            }
            if (rem > 8) {
                int gi = e0 + base + 8 + q; if (gi > elast) gi = elast;
                const int c = col[gi]; w2 = (8 + q < rem) ? val[gi] : 0.f;
                t2 = *(const uint4*)(supb + (((size_t)(unsigned)c) << 8) + fo);
            }
            if (rem > 12) {
                int gi = e0 + base + 12 + q; if (gi > elast) gi = elast;
                const int c = col[gi]; w3 = (12 + q < rem) ? val[gi] : 0.f;
                t3 = *(const uint4*)(supb + (((size_t)(unsigned)c) << 8) + fo);
            }
            { S1_FENCE(t0) S1_FMA(t0, w0) }
            if (rem > 4)  { S1_FENCE(t1) S1_FMA(t1, w1) }
            if (rem > 8)  { S1_FENCE(t2) S1_FMA(t2, w2) }
            if (rem > 12) { S1_FENCE(t3) S1_FMA(t3, w3) }
        }

        // fold quarters (f preserved by xor 16/32)
        a0 += __shfl_xor(a0, 16, 64); a1 += __shfl_xor(a1, 16, 64);
        a2 += __shfl_xor(a2, 16, 64); a3 += __shfl_xor(a3, 16, 64);
        a4 += __shfl_xor(a4, 16, 64); a5 += __shfl_xor(a5, 16, 64);
        a6 += __shfl_xor(a6, 16, 64); a7 += __shfl_xor(a7, 16, 64);
        a0 += __shfl_xor(a0, 32, 64); a1 += __shfl_xor(a1, 32, 64);
        a2 += __shfl_xor(a2, 32, 64); a3 += __shfl_xor(a3, 32, 64);
        a4 += __shfl_xor(a4, 32, 64); a5 += __shfl_xor(a5, 32, 64);
        a6 += __shfl_xor(a6, 32, 64); a7 += __shfl_xor(a7, 32, 64);

        if (q == 0) {
            const float o0 = fmaxf(a0 + ba.x, 0.f), o1 = fmaxf(a1 + ba.y, 0.f);
            const float o2 = fmaxf(a2 + ba.z, 0.f), o3 = fmaxf(a3 + ba.w, 0.f);
            const float o4 = fmaxf(a4 + bc.x, 0.f), o5 = fmaxf(a5 + bc.y, 0.f);
            const float o6 = fmaxf(a6 + bc.z, 0.f), o7 = fmaxf(a7 + bc.w, 0.f);
            uint4 pk;
            pk.x = (unsigned)f2b(o0) | ((unsigned)f2b(o1) << 16);
            pk.y = (unsigned)f2b(o2) | ((unsigned)f2b(o3) << 16);
            pk.z = (unsigned)f2b(o4) | ((unsigned)f2b(o5) << 16);
            pk.w = (unsigned)f2b(o6) | ((unsigned)f2b(o7) << 16);
            *(uint4*)&As[wave * 32 + i][f * 8] = pk;   // h row -> LDS only
        }
    }
    __syncthreads();

    // ---- phase 2: gemm2 core (24 MFMA) on As x Bs -> padded sup2 ----
    const int lm = lane & 15, quad = lane >> 4;
    f32x4 acc[2][3] = {};
#pragma unroll
    for (int ks = 0; ks < 4; ks++) {
        bf16x8 af[2], bfr[3];
#pragma unroll
        for (int i = 0; i < 2; i++)
            af[i] = *(const bf16x8*)&As[wave*32 + i*16 + lm][ks*32 + quad*8];
#pragma unroll
        for (int j = 0; j < 3; j++)
            bfr[j] = *(const bf16x8*)&Bs[j*16 + lm][ks*32 + quad*8];
#pragma unroll
        for (int i = 0; i < 2; i++)
#pragma unroll
            for (int j = 0; j < 3; j++)
                acc[i][j] = __builtin_amdgcn_mfma_f32_16x16x32_bf16(
                    af[i], bfr[j], acc[i][j], 0, 0, 0);
    }

#pragma unroll
    for (int i = 0; i < 2; i++) {
#pragma unroll
        for (int reg = 0; reg < 4; reg++) {
            const int gr = r0 + wave*32 + i*16 + quad*4 + reg;
            if (gr < nrows) {
#pragma unroll
                for (int j = 0; j < 3; j++) {
                    const int gc = j*16 + lm;          // 0..47 (40..47 are real zeros)
                    out[(size_t)gr * SUP2_LD + gc] = (bf16_t)acc[i][j][reg];
                }
            }
        }
    }
}

// ---- spmm2 + bias + log_softmax -> out[N,40] fp32 --------------------------
// wave per row, quarter-gather with dwordx2 on 128 B padded sup2 rows.
// Lanes f>=10 gather pad garbage but are fully gated (l*/s forced).
#define S2_FENCE(U) asm volatile("" : "+v"(U.x), "+v"(U.y));
#define S2_FMA(U, V)                                   \
    a0 = fmaf(V, blo(U.x), a0); a1 = fmaf(V, bhi(U.x), a1); \
    a2 = fmaf(V, blo(U.y), a2); a3 = fmaf(V, bhi(U.y), a3);

__global__ __launch_bounds__(256) void k_spmm2_lsm(
    const int* __restrict__ row_ptr, const int* __restrict__ col,
    const float* __restrict__ val, const bf16_t* __restrict__ sup2,
    const float* __restrict__ b2, float* __restrict__ out, int nrows)
{
    const int wid  = (blockIdx.x * blockDim.x + threadIdx.x) >> 6;
    const int lane = threadIdx.x & 63;
    if (wid >= nrows) return;
    const int q = lane >> 4;
    const int f = lane & 15;            // classes 4f..4f+3 (valid for f<10)
    const int e0 = __builtin_amdgcn_readfirstlane(row_ptr[wid]);
    const int e1 = __builtin_amdgcn_readfirstlane(row_ptr[wid + 1]);
    const int n  = e1 - e0;
    const char* supb = (const char*)sup2;
    const int fo = f * 8;               // byte offset within 128 B row

    float a0=0.f,a1=0.f,a2=0.f,a3=0.f;

    int base = 0;
    for (; base + 16 <= n; base += 16) {
        const int i0 = e0 + base + q;
        const int   c0 = __builtin_nontemporal_load(col + i0);
        const float v0 = __builtin_nontemporal_load(val + i0);
        const int   c1 = __builtin_nontemporal_load(col + i0 + 4);
        const float v1 = __builtin_nontemporal_load(val + i0 + 4);
        const int   c2 = __builtin_nontemporal_load(col + i0 + 8);
        const float v2 = __builtin_nontemporal_load(val + i0 + 8);
        const int   c3 = __builtin_nontemporal_load(col + i0 + 12);
        const float v3 = __builtin_nontemporal_load(val + i0 + 12);
        uint2 u0 = *(const uint2*)(supb + (((size_t)(unsigned)c0) << 7) + fo);
        uint2 u1 = *(const uint2*)(supb + (((size_t)(unsigned)c1) << 7) + fo);
        uint2 u2 = *(const uint2*)(supb + (((size_t)(unsigned)c2) << 7) + fo);
        uint2 u3 = *(const uint2*)(supb + (((size_t)(unsigned)c3) << 7) + fo);
        S2_FENCE(u0) S2_FMA(u0, v0)
        S2_FENCE(u1) S2_FMA(u1, v1)
        S2_FENCE(u2) S2_FMA(u2, v2)
        S2_FENCE(u3) S2_FMA(u3, v3)
    }
    const int rem = n - base;
    if (rem > 0) {
        const int elast = e1 - 1;
        uint2 t0, t1, t2, t3;
        float w0 = 0.f, w1 = 0.f, w2 = 0.f, w3 = 0.f;
        {
            int gi = e0 + base + q; if (gi > elast) gi = elast;
            const int c = col[gi]; w0 = (q < rem) ? val[gi] : 0.f;
            t0 = *(const uint2*)(supb + (((size_t)(unsigned)c) << 7) + fo);
        }
        if (rem > 4) {
            int gi = e0 + base + 4 + q; if (gi > elast) gi = elast;
            const int c = col[gi]; w1 = (4 + q < rem) ? val[gi] : 0.f;
            t1 = *(const uint2*)(supb + (((size_t)(unsigned)c) << 7) + fo);
        }
        if (rem > 8) {
            int gi = e0 + base + 8 + q; if (gi > elast) gi = elast;
            const int c = col[gi]; w2 = (8 + q < rem) ? val[gi] : 0.f;
            t2 = *(const uint2*)(supb + (((size_t)(unsigned)c) << 7) + fo);
        }
        if (rem > 12) {
            int gi = e0 + base + 12 + q; if (gi > elast) gi = elast;
            const int c = col[gi]; w3 = (12 + q < rem) ? val[gi] : 0.f;
            t3 = *(const uint2*)(supb + (((size_t)(unsigned)c) << 7) + fo);
        }
        { S2_FENCE(t0) S2_FMA(t0, w0) }
        if (rem > 4)  { S2_FENCE(t1) S2_FMA(t1, w1) }
        if (rem > 8)  { S2_FENCE(t2) S2_FMA(t2, w2) }
        if (rem > 12) { S2_FENCE(t3) S2_FMA(t3, w3) }
    }

    // fold quarters
    a0 += __shfl_xor(a0, 16, 64); a1 += __shfl_xor(a1, 16, 64);
    a2 += __shfl_xor(a2, 16, 64); a3 += __shfl_xor(a3, 16, 64);
    a0 += __shfl_xor(a0, 32, 64); a1 += __shfl_xor(a1, 32, 64);
    a2 += __shfl_xor(a2, 32, 64); a3 += __shfl_xor(a3, 32, 64);

    // bias + log_softmax across the 16-lane f dimension (classes 4f..4f+3)
    const bool av = (f < 10);
    float l0 = -INFINITY, l1 = -INFINITY, l2 = -INFINITY, l3 = -INFINITY;
    if (av) {
        const float4 bb = *(const float4*)(b2 + f * 4);
        l0 = a0 + bb.x; l1 = a1 + bb.y; l2 = a2 + bb.z; l3 = a3 + bb.w;
    }
    float m = fmaxf(fmaxf(l0, l1), fmaxf(l2, l3));
    m = fmaxf(m, __shfl_xor(m, 1, 64));
    m = fmaxf(m, __shfl_xor(m, 2, 64));
    m = fmaxf(m, __shfl_xor(m, 4, 64));
    m = fmaxf(m, __shfl_xor(m, 8, 64));
    float s = av ? (__expf(l0 - m) + __expf(l1 - m) + __expf(l2 - m) + __expf(l3 - m)) : 0.f;
    s += __shfl_xor(s, 1, 64);
    s += __shfl_xor(s, 2, 64);
    s += __shfl_xor(s, 4, 64);
    s += __shfl_xor(s, 8, 64);

    if (av && q == 0) {
        const float lse = m + __logf(s);
        f32x4e o;
        o.x = l0 - lse; o.y = l1 - lse; o.z = l2 - lse; o.w = l3 - lse;
        f32x4e* p = (f32x4e*)(out + (size_t)wid * GCN_NCLASS + f * 4);
        __builtin_nontemporal_store(o, p);
    }
}

// ---------------------------------------------------------------------------
extern "C" void kernel_launch(void* const* d_in, const int* in_sizes, int n_in,
                              void* d_out, int out_size, void* d_ws, size_t ws_size,
                              hipStream_t stream)
{
    const float* x       = (const float*)d_in[0];
    const int*   adj_row = (const int*)  d_in[1];
    const int*   adj_col = (const int*)  d_in[2];
    const float* adj_val = (const float*)d_in[3];
    // d_in[4] = i (unused)
    const float* W1 = (const float*)d_in[5];
    const float* b1 = (const float*)d_in[6];
    const float* W2 = (const float*)d_in[7];
    const float* b2 = (const float*)d_in[8];
    float* out = (float*)d_out;

    const int N = in_sizes[0] / GCN_NFEAT;   // 100000
    const int E = in_sizes[1];               // 3200000

    // workspace layout (1 KiB aligned chunks)
    char* ws = (char*)d_ws;
    size_t off = 0;
    int* row_ptr = (int*)(ws + off);
    off += (((size_t)(N + 1) * sizeof(int)) + 1023) & ~(size_t)1023;
    bf16_t* w1t = (bf16_t*)(ws + off);                 // 128*256 bf16
    off += ((size_t)GCN_NHID * GCN_NFEAT * 2 + 1023) & ~(size_t)1023;
    bf16_t* w2t = (bf16_t*)(ws + off);                 // 48*128 bf16
    off += ((size_t)48 * GCN_NHID * 2 + 1023) & ~(size_t)1023;
    bf16_t* sup1 = (bf16_t*)(ws + off);                // N*128 bf16
    off += ((size_t)N * GCN_NHID * 2 + 1023) & ~(size_t)1023;
    bf16_t* sup2 = (bf16_t*)(ws + off);                // N*64 bf16 (padded rows)
    // NOTE: sup2 must NOT alias sup1 (fused kernel writes sup2 while other
    // blocks still gather sup1 rows).

    const int rb = (N + 1 + 255) / 256;                // row_ptr blocks
    k_prep<<<rb + 128 + 24, 256, 0, stream>>>(adj_row, row_ptr, W1, w1t, W2, w2t,
                                              N, E, rb);
    k_gemm1<<<(N + 127) / 128, 256, 0, stream>>>(x, w1t, sup1, N);
    k_spmm1_g2<<<(N + 127) / 128, 256, 0, stream>>>(row_ptr, adj_col, adj_val,
                                                    sup1, b1, w2t, sup2, N);
    k_spmm2_lsm<<<(N + 3) / 4, 256, 0, stream>>>(row_ptr, adj_col, adj_val,
                                                 sup2, b2, out, N);
}

// Round 6
// 425.954 us; speedup vs baseline: 1.2420x; 1.2420x over previous
//
#include <hip/hip_runtime.h>
#include <hip/hip_bf16.h>
#include <math.h>

// ---------------------------------------------------------------------------
// GCN forward: out = log_softmax( A@( relu(A@(x@W1)+b1) @ W2 ) + b2 )
// Round 10: REVERT the spmm1+gemm2 fusion (R9: occupancy 72->20%, fetch path
// starved, 223 us). Gather kernels must stay at high occupancy. Restore the
// best-measured config (R5-bench 383.9 us): standalone quarter-gather spmm1
// (105 us, fetch-bound at 3.75 TB/s L2<-L3), R1-structure gemm2+spmm2 (tight
// 80 B sup2 rows). Keep: merged prep (1 dispatch), NT loads on stream-once
// col/val/x (preserve L2 for gather rows), NT ext_vector compile fix.
// ---------------------------------------------------------------------------

#define GCN_NFEAT 256
#define GCN_NHID  128
#define GCN_NCLASS 40

typedef __bf16 bf16_t;
typedef bf16_t bf16x8 __attribute__((ext_vector_type(8)));
typedef float  f32x4  __attribute__((ext_vector_type(4)));
typedef float  f32x4e __attribute__((ext_vector_type(4)));  // for nontemporal

static __device__ __forceinline__ unsigned short f2b(float f) {
    bf16_t b = (bf16_t)f;
    return *(unsigned short*)&b;
}
static __device__ __forceinline__ float blo(unsigned int u) {
    return __uint_as_float(u << 16);
}
static __device__ __forceinline__ float bhi(unsigned int u) {
    return __uint_as_float(u & 0xffff0000u);
}

// ---- merged prep: row_ptr + W1t + W2t in one dispatch ----------------------
__global__ __launch_bounds__(256) void k_prep(
    const int* __restrict__ row, int* __restrict__ row_ptr,
    const float* __restrict__ w1, bf16_t* __restrict__ w1t,
    const float* __restrict__ w2, bf16_t* __restrict__ w2t,
    int n_rows, int n_edges, int rb)
{
    const int b = blockIdx.x;
    if (b < rb) {
        // row_ptr[r] = lower_bound(adj_row, r)
        int r = b * 256 + threadIdx.x;
        if (r > n_rows) return;
        int lo = 0, hi = n_edges;
        while (lo < hi) {
            int mid = (lo + hi) >> 1;
            if (row[mid] < r) lo = mid + 1; else hi = mid;
        }
        row_ptr[r] = lo;
    } else if (b < rb + 128) {
        // W1t[128][256]
        int idx = (b - rb) * 256 + threadIdx.x;   // 32768 total
        int c = idx & 127;
        int k = idx >> 7;
        w1t[(size_t)c * GCN_NFEAT + k] = (bf16_t)w1[(size_t)k * GCN_NHID + c];
    } else {
        // W2t[48][128], cols 40..47 zero
        int idx = (b - rb - 128) * 256 + threadIdx.x;  // 6144 total
        if (idx >= 48 * GCN_NHID) return;
        int c = idx / GCN_NHID;
        int k = idx - c * GCN_NHID;
        float v = (c < GCN_NCLASS) ? w2[(size_t)k * GCN_NCLASS + c] : 0.f;
        w2t[idx] = (bf16_t)v;
    }
}

// ---- GEMM1 (MFMA): sup1_bf16[N,128] = bf16( x[N,256] @ W1 ) ----------------
__global__ __launch_bounds__(256) void k_gemm1(
    const float* __restrict__ x, const bf16_t* __restrict__ w1t,
    bf16_t* __restrict__ out, int nrows)
{
    __shared__ __align__(16) bf16_t As[128][72];   // [row][k]
    __shared__ __align__(16) bf16_t Bs[128][72];   // [col][k]

    const int tid  = threadIdx.x;
    const int wave = tid >> 6, lane = tid & 63;
    const int wm = wave >> 1, wn = wave & 1;
    const int lm = lane & 15, quad = lane >> 4;
    const int r0 = blockIdx.x * 128;

    f32x4 acc[4][4] = {};

    for (int k0 = 0; k0 < GCN_NFEAT; k0 += 64) {
        {
            const int row = tid >> 1, half = tid & 1;
            const int gr = r0 + row;
            union { bf16_t b[32]; uint4 q[4]; } t;
            if (gr < nrows) {
                const f32x4e* p = (const f32x4e*)(x + (size_t)gr * GCN_NFEAT + k0 + half * 32);
#pragma unroll
                for (int i = 0; i < 8; i++) {
                    f32x4e v = __builtin_nontemporal_load(p + i);
                    t.b[i*4+0] = (bf16_t)v.x; t.b[i*4+1] = (bf16_t)v.y;
                    t.b[i*4+2] = (bf16_t)v.z; t.b[i*4+3] = (bf16_t)v.w;
                }
            } else {
#pragma unroll
                for (int i = 0; i < 4; i++) t.q[i] = make_uint4(0,0,0,0);
            }
            uint4* dst = (uint4*)&As[row][half * 32];
#pragma unroll
            for (int i = 0; i < 4; i++) dst[i] = t.q[i];
        }
        {
            const int colc = tid >> 1, half = tid & 1;
            const uint4* src = (const uint4*)(w1t + (size_t)colc * GCN_NFEAT + k0 + half * 32);
            uint4* dst = (uint4*)&Bs[colc][half * 32];
#pragma unroll
            for (int i = 0; i < 4; i++) dst[i] = src[i];
        }
        __syncthreads();

#pragma unroll
        for (int ks = 0; ks < 2; ks++) {
            bf16x8 af[4], bfr[4];
#pragma unroll
            for (int i = 0; i < 4; i++)
                af[i] = *(const bf16x8*)&As[wm*64 + i*16 + lm][ks*32 + quad*8];
#pragma unroll
            for (int j = 0; j < 4; j++)
                bfr[j] = *(const bf16x8*)&Bs[wn*64 + j*16 + lm][ks*32 + quad*8];
#pragma unroll
            for (int i = 0; i < 4; i++)
#pragma unroll
                for (int j = 0; j < 4; j++)
                    acc[i][j] = __builtin_amdgcn_mfma_f32_16x16x32_bf16(
                        af[i], bfr[j], acc[i][j], 0, 0, 0);
        }
        __syncthreads();
    }

#pragma unroll
    for (int i = 0; i < 4; i++) {
#pragma unroll
        for (int reg = 0; reg < 4; reg++) {
            const int gr = r0 + wm*64 + i*16 + quad*4 + reg;
            if (gr < nrows) {
#pragma unroll
                for (int j = 0; j < 4; j++) {
                    const int gc = wn*64 + j*16 + lm;
                    out[(size_t)gr * GCN_NHID + gc] = (bf16_t)acc[i][j][reg];
                }
            }
        }
    }
}

// ---- spmm1: h_bf16[r,:] = relu( sum_e val[e]*sup1[col[e],:] + b1 ) ---------
// wave per row, quarter-gather: quarter q = lane>>4 handles edge 4k+q of each
// group; lane f = lane&15 owns features 8f..8f+7 (one dwordx4 of the row).
#define S1_FENCE(U) asm volatile("" : "+v"(U.x), "+v"(U.y), "+v"(U.z), "+v"(U.w));
#define S1_FMA(U, V)                                   \
    a0 = fmaf(V, blo(U.x), a0); a1 = fmaf(V, bhi(U.x), a1); \
    a2 = fmaf(V, blo(U.y), a2); a3 = fmaf(V, bhi(U.y), a3); \
    a4 = fmaf(V, blo(U.z), a4); a5 = fmaf(V, bhi(U.z), a5); \
    a6 = fmaf(V, blo(U.w), a6); a7 = fmaf(V, bhi(U.w), a7);

__global__ __launch_bounds__(256) void k_spmm1(
    const int* __restrict__ row_ptr, const int* __restrict__ col,
    const float* __restrict__ val, const bf16_t* __restrict__ sup,
    const float* __restrict__ b1, unsigned int* __restrict__ h, int nrows)
{
    const int wid  = (blockIdx.x * blockDim.x + threadIdx.x) >> 6;
    const int lane = threadIdx.x & 63;
    if (wid >= nrows) return;
    const int q = lane >> 4;            // quarter: which edge of the group
    const int f = lane & 15;            // feature block 8f..8f+7
    const int e0 = __builtin_amdgcn_readfirstlane(row_ptr[wid]);
    const int e1 = __builtin_amdgcn_readfirstlane(row_ptr[wid + 1]);
    const int n  = e1 - e0;
    const char* supb = (const char*)sup;
    const int fo = f * 16;              // byte offset within row

    float a0=0.f,a1=0.f,a2=0.f,a3=0.f,a4=0.f,a5=0.f,a6=0.f,a7=0.f;

    int base = 0;
    // main: 16-edge chunks, 4 dwordx4 gathers in flight
    for (; base + 16 <= n; base += 16) {
        const int i0 = e0 + base + q;
        const int   c0 = __builtin_nontemporal_load(col + i0);
        const float v0 = __builtin_nontemporal_load(val + i0);
        const int   c1 = __builtin_nontemporal_load(col + i0 + 4);
        const float v1 = __builtin_nontemporal_load(val + i0 + 4);
        const int   c2 = __builtin_nontemporal_load(col + i0 + 8);
        const float v2 = __builtin_nontemporal_load(val + i0 + 8);
        const int   c3 = __builtin_nontemporal_load(col + i0 + 12);
        const float v3 = __builtin_nontemporal_load(val + i0 + 12);
        uint4 u0 = *(const uint4*)(supb + (((size_t)(unsigned)c0) << 8) + fo);
        uint4 u1 = *(const uint4*)(supb + (((size_t)(unsigned)c1) << 8) + fo);
        uint4 u2 = *(const uint4*)(supb + (((size_t)(unsigned)c2) << 8) + fo);
        uint4 u3 = *(const uint4*)(supb + (((size_t)(unsigned)c3) << 8) + fo);
        S1_FENCE(u0) S1_FMA(u0, v0)
        S1_FENCE(u1) S1_FMA(u1, v1)
        S1_FENCE(u2) S1_FMA(u2, v2)
        S1_FENCE(u3) S1_FMA(u3, v3)
    }
    // tail: up to 15 edges as 1-4 guarded groups (all issued before consume)
    const int rem = n - base;
    if (rem > 0) {
        const int elast = e1 - 1;
        uint4 t0, t1, t2, t3;
        float w0 = 0.f, w1 = 0.f, w2 = 0.f, w3 = 0.f;
        {
            int gi = e0 + base + q; if (gi > elast) gi = elast;
            const int c = col[gi]; w0 = (q < rem) ? val[gi] : 0.f;
            t0 = *(const uint4*)(supb + (((size_t)(unsigned)c) << 8) + fo);
        }
        if (rem > 4) {
            int gi = e0 + base + 4 + q; if (gi > elast) gi = elast;
            const int c = col[gi]; w1 = (4 + q < rem) ? val[gi] : 0.f;
            t1 = *(const uint4*)(supb + (((size_t)(unsigned)c) << 8) + fo);
        }
        if (rem > 8) {
            int gi = e0 + base + 8 + q; if (gi > elast) gi = elast;
            const int c = col[gi]; w2 = (8 + q < rem) ? val[gi] : 0.f;
            t2 = *(const uint4*)(supb + (((size_t)(unsigned)c) << 8) + fo);
        }
        if (rem > 12) {
            int gi = e0 + base + 12 + q; if (gi > elast) gi = elast;
            const int c = col[gi]; w3 = (12 + q < rem) ? val[gi] : 0.f;
            t3 = *(const uint4*)(supb + (((size_t)(unsigned)c) << 8) + fo);
        }
        { S1_FENCE(t0) S1_FMA(t0, w0) }
        if (rem > 4)  { S1_FENCE(t1) S1_FMA(t1, w1) }
        if (rem > 8)  { S1_FENCE(t2) S1_FMA(t2, w2) }
        if (rem > 12) { S1_FENCE(t3) S1_FMA(t3, w3) }
    }

    // fold the 4 quarters (f preserved by xor 16/32)
    a0 += __shfl_xor(a0, 16, 64); a1 += __shfl_xor(a1, 16, 64);
    a2 += __shfl_xor(a2, 16, 64); a3 += __shfl_xor(a3, 16, 64);
    a4 += __shfl_xor(a4, 16, 64); a5 += __shfl_xor(a5, 16, 64);
    a6 += __shfl_xor(a6, 16, 64); a7 += __shfl_xor(a7, 16, 64);
    a0 += __shfl_xor(a0, 32, 64); a1 += __shfl_xor(a1, 32, 64);
    a2 += __shfl_xor(a2, 32, 64); a3 += __shfl_xor(a3, 32, 64);
    a4 += __shfl_xor(a4, 32, 64); a5 += __shfl_xor(a5, 32, 64);
    a6 += __shfl_xor(a6, 32, 64); a7 += __shfl_xor(a7, 32, 64);

    if (q == 0) {
        const float4 ba = *(const float4*)(b1 + f * 8);
        const float4 bc = *(const float4*)(b1 + f * 8 + 4);
        const float o0 = fmaxf(a0 + ba.x, 0.f), o1 = fmaxf(a1 + ba.y, 0.f);
        const float o2 = fmaxf(a2 + ba.z, 0.f), o3 = fmaxf(a3 + ba.w, 0.f);
        const float o4 = fmaxf(a4 + bc.x, 0.f), o5 = fmaxf(a5 + bc.y, 0.f);
        const float o6 = fmaxf(a6 + bc.z, 0.f), o7 = fmaxf(a7 + bc.w, 0.f);
        uint4 pk;
        pk.x = (unsigned)f2b(o0) | ((unsigned)f2b(o1) << 16);
        pk.y = (unsigned)f2b(o2) | ((unsigned)f2b(o3) << 16);
        pk.z = (unsigned)f2b(o4) | ((unsigned)f2b(o5) << 16);
        pk.w = (unsigned)f2b(o6) | ((unsigned)f2b(o7) << 16);
        *(uint4*)(h + ((unsigned)wid << 6) + (f << 2)) = pk;
    }
}

// ---- GEMM2 (MFMA): sup2_bf16[N,40] = bf16( h[N,128] @ W2 ) -----------------
__global__ __launch_bounds__(256) void k_gemm2(
    const bf16_t* __restrict__ h, const bf16_t* __restrict__ w2t,
    bf16_t* __restrict__ out, int nrows)
{
    __shared__ __align__(16) bf16_t As[128][136];  // [row][k]
    __shared__ __align__(16) bf16_t Bs[48][136];   // [col][k]

    const int tid  = threadIdx.x;
    const int wave = tid >> 6, lane = tid & 63;
    const int lm = lane & 15, quad = lane >> 4;
    const int r0 = blockIdx.x * 128;

    {
        const int row = tid >> 1, half = tid & 1;
        const int gr = r0 + row;
        uint4* dst = (uint4*)&As[row][half * 64];
        if (gr < nrows) {
            const uint4* src = (const uint4*)(h + (size_t)gr * GCN_NHID + half * 64);
#pragma unroll
            for (int i = 0; i < 8; i++) dst[i] = src[i];
        } else {
#pragma unroll
            for (int i = 0; i < 8; i++) dst[i] = make_uint4(0,0,0,0);
        }
    }
    // stage B: 48 rows x 16 uint4 (full 256 B row)
    for (int idx = tid; idx < 48 * 16; idx += 256) {
        const int c = idx >> 4, seg = idx & 15;
        ((uint4*)&Bs[c][0])[seg] = ((const uint4*)(w2t + (size_t)c * GCN_NHID))[seg];
    }
    __syncthreads();

    f32x4 acc[2][3] = {};
#pragma unroll
    for (int ks = 0; ks < 4; ks++) {
        bf16x8 af[2], bfr[3];
#pragma unroll
        for (int i = 0; i < 2; i++)
            af[i] = *(const bf16x8*)&As[wave*32 + i*16 + lm][ks*32 + quad*8];
#pragma unroll
        for (int j = 0; j < 3; j++)
            bfr[j] = *(const bf16x8*)&Bs[j*16 + lm][ks*32 + quad*8];
#pragma unroll
        for (int i = 0; i < 2; i++)
#pragma unroll
            for (int j = 0; j < 3; j++)
                acc[i][j] = __builtin_amdgcn_mfma_f32_16x16x32_bf16(
                    af[i], bfr[j], acc[i][j], 0, 0, 0);
    }

#pragma unroll
    for (int i = 0; i < 2; i++) {
#pragma unroll
        for (int reg = 0; reg < 4; reg++) {
            const int gr = r0 + wave*32 + i*16 + quad*4 + reg;
            if (gr < nrows) {
#pragma unroll
                for (int j = 0; j < 3; j++) {
                    const int gc = j*16 + lm;
                    if (gc < GCN_NCLASS)
                        out[(size_t)gr * GCN_NCLASS + gc] = (bf16_t)acc[i][j][reg];
                }
            }
        }
    }
}

// ---- spmm2 + bias + log_softmax -> out[N,40] fp32 --------------------------
// 3 rows per wave: group g = lane/20 handles row wid*3+g, li = lane%20 owns
// classes {2li, 2li+1} packed in one uint. 8-edge unroll (24 gathers in
// flight per wave). Tight 80 B sup2 rows (R1 structure - best measured).
__global__ __launch_bounds__(256) void k_spmm2_lsm(
    const int* __restrict__ row_ptr, const int* __restrict__ col,
    const float* __restrict__ val, const unsigned int* __restrict__ sup2,
    const float* __restrict__ b2, float* __restrict__ out, int nrows)
{
    const int wid  = (blockIdx.x * blockDim.x + threadIdx.x) >> 6;
    const int lane = threadIdx.x & 63;
    const int g    = lane / 20;            // 0..2 valid, 3 = idle lanes 60-63
    const int li   = lane - g * 20;
    const int r    = wid * 3 + g;
    const bool active = (g < 3) && (r < nrows);

    int e0 = 0, e1 = 0;
    if (active) { e0 = row_ptr[r]; e1 = row_ptr[r + 1]; }

    float ax = 0.f, ay = 0.f;
    int e = e0;
    for (; e + 7 < e1; e += 8) {
        const int c0 = __builtin_nontemporal_load(col + e);
        const int c1 = __builtin_nontemporal_load(col + e + 1);
        const int c2 = __builtin_nontemporal_load(col + e + 2);
        const int c3 = __builtin_nontemporal_load(col + e + 3);
        const int c4 = __builtin_nontemporal_load(col + e + 4);
        const int c5 = __builtin_nontemporal_load(col + e + 5);
        const int c6 = __builtin_nontemporal_load(col + e + 6);
        const int c7 = __builtin_nontemporal_load(col + e + 7);
        const float v0 = __builtin_nontemporal_load(val + e);
        const float v1 = __builtin_nontemporal_load(val + e + 1);
        const float v2 = __builtin_nontemporal_load(val + e + 2);
        const float v3 = __builtin_nontemporal_load(val + e + 3);
        const float v4 = __builtin_nontemporal_load(val + e + 4);
        const float v5 = __builtin_nontemporal_load(val + e + 5);
        const float v6 = __builtin_nontemporal_load(val + e + 6);
        const float v7 = __builtin_nontemporal_load(val + e + 7);
        const unsigned int u0 = sup2[(unsigned)(c0 * 20) + li];
        const unsigned int u1 = sup2[(unsigned)(c1 * 20) + li];
        const unsigned int u2 = sup2[(unsigned)(c2 * 20) + li];
        const unsigned int u3 = sup2[(unsigned)(c3 * 20) + li];
        const unsigned int u4 = sup2[(unsigned)(c4 * 20) + li];
        const unsigned int u5 = sup2[(unsigned)(c5 * 20) + li];
        const unsigned int u6 = sup2[(unsigned)(c6 * 20) + li];
        const unsigned int u7 = sup2[(unsigned)(c7 * 20) + li];
        ax = fmaf(v0, blo(u0), ax); ay = fmaf(v0, bhi(u0), ay);
        ax = fmaf(v1, blo(u1), ax); ay = fmaf(v1, bhi(u1), ay);
        ax = fmaf(v2, blo(u2), ax); ay = fmaf(v2, bhi(u2), ay);
        ax = fmaf(v3, blo(u3), ax); ay = fmaf(v3, bhi(u3), ay);
        ax = fmaf(v4, blo(u4), ax); ay = fmaf(v4, bhi(u4), ay);
        ax = fmaf(v5, blo(u5), ax); ay = fmaf(v5, bhi(u5), ay);
        ax = fmaf(v6, blo(u6), ax); ay = fmaf(v6, bhi(u6), ay);
        ax = fmaf(v7, blo(u7), ax); ay = fmaf(v7, bhi(u7), ay);
    }
    for (; e + 3 < e1; e += 4) {
        const int c0 = col[e],   c1 = col[e+1], c2 = col[e+2], c3 = col[e+3];
        const float v0 = val[e], v1 = val[e+1], v2 = val[e+2], v3 = val[e+3];
        const unsigned int u0 = sup2[(unsigned)(c0 * 20) + li];
        const unsigned int u1 = sup2[(unsigned)(c1 * 20) + li];
        const unsigned int u2 = sup2[(unsigned)(c2 * 20) + li];
        const unsigned int u3 = sup2[(unsigned)(c3 * 20) + li];
        ax = fmaf(v0, blo(u0), ax); ay = fmaf(v0, bhi(u0), ay);
        ax = fmaf(v1, blo(u1), ax); ay = fmaf(v1, bhi(u1), ay);
        ax = fmaf(v2, blo(u2), ax); ay = fmaf(v2, bhi(u2), ay);
        ax = fmaf(v3, blo(u3), ax); ay = fmaf(v3, bhi(u3), ay);
    }
    for (; e < e1; e++) {
        const unsigned int u = sup2[(unsigned)(col[e] * 20) + li];
        const float v = val[e];
        ax = fmaf(v, blo(u), ax); ay = fmaf(v, bhi(u), ay);
    }

    float l0 = -INFINITY, l1 = -INFINITY;
    if (active) {
        l0 = ax + b2[li * 2];
        l1 = ay + b2[li * 2 + 1];
    }

    // group-local (20-lane) shuffle reductions
    float m = fmaxf(l0, l1);
#pragma unroll
    for (int off = 16; off >= 1; off >>= 1) {
        const float t = __shfl_down(m, off, 64);
        if (li + off < 20) m = fmaxf(m, t);
    }
    m = __shfl(m, g * 20, 64);   // broadcast group max

    float s = active ? (__expf(l0 - m) + __expf(l1 - m)) : 0.f;
#pragma unroll
    for (int off = 16; off >= 1; off >>= 1) {
        const float t = __shfl_down(s, off, 64);
        if (li + off < 20) s += t;
    }
    s = __shfl(s, g * 20, 64);

    if (active) {
        const float lse = m + __logf(s);
        float* p = out + (size_t)r * GCN_NCLASS + li * 2;
        p[0] = l0 - lse;
        p[1] = l1 - lse;
    }
}

// ---------------------------------------------------------------------------
extern "C" void kernel_launch(void* const* d_in, const int* in_sizes, int n_in,
                              void* d_out, int out_size, void* d_ws, size_t ws_size,
                              hipStream_t stream)
{
    const float* x       = (const float*)d_in[0];
    const int*   adj_row = (const int*)  d_in[1];
    const int*   adj_col = (const int*)  d_in[2];
    const float* adj_val = (const float*)d_in[3];
    // d_in[4] = i (unused)
    const float* W1 = (const float*)d_in[5];
    const float* b1 = (const float*)d_in[6];
    const float* W2 = (const float*)d_in[7];
    const float* b2 = (const float*)d_in[8];
    float* out = (float*)d_out;

    const int N = in_sizes[0] / GCN_NFEAT;   // 100000
    const int E = in_sizes[1];               // 3200000

    // workspace layout (1 KiB aligned chunks)
    char* ws = (char*)d_ws;
    size_t off = 0;
    int* row_ptr = (int*)(ws + off);
    off += (((size_t)(N + 1) * sizeof(int)) + 1023) & ~(size_t)1023;
    bf16_t* w1t = (bf16_t*)(ws + off);                 // 128*256 bf16
    off += ((size_t)GCN_NHID * GCN_NFEAT * 2 + 1023) & ~(size_t)1023;
    bf16_t* w2t = (bf16_t*)(ws + off);                 // 48*128 bf16
    off += ((size_t)48 * GCN_NHID * 2 + 1023) & ~(size_t)1023;
    bf16_t* sup1 = (bf16_t*)(ws + off);                // N*128 bf16
    off += ((size_t)N * GCN_NHID * 2 + 1023) & ~(size_t)1023;
    bf16_t* h = (bf16_t*)(ws + off);                   // N*128 bf16
    bf16_t* sup2 = sup1;                               // reuse sup1 (N*40 bf16)

    const int rb = (N + 1 + 255) / 256;                // row_ptr blocks
    k_prep<<<rb + 128 + 24, 256, 0, stream>>>(adj_row, row_ptr, W1, w1t, W2, w2t,
                                              N, E, rb);
    k_gemm1<<<(N + 127) / 128, 256, 0, stream>>>(x, w1t, sup1, N);
    k_spmm1<<<(N + 3) / 4, 256, 0, stream>>>(row_ptr, adj_col, adj_val,
                                             sup1, b1, (unsigned int*)h, N);
    k_gemm2<<<(N + 127) / 128, 256, 0, stream>>>(h, w2t, sup2, N);
    const int nw2 = (N + 2) / 3;                       // waves for spmm2
    k_spmm2_lsm<<<(nw2 + 3) / 4, 256, 0, stream>>>(row_ptr, adj_col, adj_val,
                                                   (const unsigned int*)sup2, b2, out, N);
}

// Round 7
// 382.268 us; speedup vs baseline: 1.3840x; 1.1143x over previous
//
#include <hip/hip_runtime.h>
#include <hip/hip_bf16.h>
#include <math.h>

// ---------------------------------------------------------------------------
// GCN forward: out = log_softmax( A@( relu(A@(x@W1)+b1) @ W2 ) + b2 )
// Round 11: best-of-measured assembly, no new mechanisms.
// - NO nontemporal hints anywhere (R10: NT on col/val broke adjacent-row L2
//   line reuse, +20MB fetch, +6us on spmm1, +25us on rest. spmm1 time =
//   FETCH/3.42 GB/us exactly - fill-path bound).
// - spmm1: R7 quarter-gather, plain loads (measured 105.0 us).
// - gemm1/gemm2/spmm2: R5-bench structure, plain loads (measured rest 278 us;
//   tight 80 B sup2 rows beat 128 B padded by ~10 us).
// - merged prep (1 dispatch, -2 launches).
// ---------------------------------------------------------------------------

#define GCN_NFEAT 256
#define GCN_NHID  128
#define GCN_NCLASS 40

typedef __bf16 bf16_t;
typedef bf16_t bf16x8 __attribute__((ext_vector_type(8)));
typedef float  f32x4  __attribute__((ext_vector_type(4)));

static __device__ __forceinline__ unsigned short f2b(float f) {
    bf16_t b = (bf16_t)f;
    return *(unsigned short*)&b;
}
static __device__ __forceinline__ float blo(unsigned int u) {
    return __uint_as_float(u << 16);
}
static __device__ __forceinline__ float bhi(unsigned int u) {
    return __uint_as_float(u & 0xffff0000u);
}

// ---- merged prep: row_ptr + W1t + W2t in one dispatch ----------------------
__global__ __launch_bounds__(256) void k_prep(
    const int* __restrict__ row, int* __restrict__ row_ptr,
    const float* __restrict__ w1, bf16_t* __restrict__ w1t,
    const float* __restrict__ w2, bf16_t* __restrict__ w2t,
    int n_rows, int n_edges, int rb)
{
    const int b = blockIdx.x;
    if (b < rb) {
        // row_ptr[r] = lower_bound(adj_row, r)
        int r = b * 256 + threadIdx.x;
        if (r > n_rows) return;
        int lo = 0, hi = n_edges;
        while (lo < hi) {
            int mid = (lo + hi) >> 1;
            if (row[mid] < r) lo = mid + 1; else hi = mid;
        }
        row_ptr[r] = lo;
    } else if (b < rb + 128) {
        // W1t[128][256]
        int idx = (b - rb) * 256 + threadIdx.x;   // 32768 total
        int c = idx & 127;
        int k = idx >> 7;
        w1t[(size_t)c * GCN_NFEAT + k] = (bf16_t)w1[(size_t)k * GCN_NHID + c];
    } else {
        // W2t[48][128], cols 40..47 zero
        int idx = (b - rb - 128) * 256 + threadIdx.x;  // 6144 total
        if (idx >= 48 * GCN_NHID) return;
        int c = idx / GCN_NHID;
        int k = idx - c * GCN_NHID;
        float v = (c < GCN_NCLASS) ? w2[(size_t)k * GCN_NCLASS + c] : 0.f;
        w2t[idx] = (bf16_t)v;
    }
}

// ---- GEMM1 (MFMA): sup1_bf16[N,128] = bf16( x[N,256] @ W1 ) ----------------
__global__ __launch_bounds__(256) void k_gemm1(
    const float* __restrict__ x, const bf16_t* __restrict__ w1t,
    bf16_t* __restrict__ out, int nrows)
{
    __shared__ __align__(16) bf16_t As[128][72];   // [row][k]
    __shared__ __align__(16) bf16_t Bs[128][72];   // [col][k]

    const int tid  = threadIdx.x;
    const int wave = tid >> 6, lane = tid & 63;
    const int wm = wave >> 1, wn = wave & 1;
    const int lm = lane & 15, quad = lane >> 4;
    const int r0 = blockIdx.x * 128;

    f32x4 acc[4][4] = {};

    for (int k0 = 0; k0 < GCN_NFEAT; k0 += 64) {
        {
            const int row = tid >> 1, half = tid & 1;
            const int gr = r0 + row;
            union { bf16_t b[32]; uint4 q[4]; } t;
            if (gr < nrows) {
                const float* p = x + (size_t)gr * GCN_NFEAT + k0 + half * 32;
#pragma unroll
                for (int i = 0; i < 8; i++) {
                    float4 v = ((const float4*)p)[i];
                    t.b[i*4+0] = (bf16_t)v.x; t.b[i*4+1] = (bf16_t)v.y;
                    t.b[i*4+2] = (bf16_t)v.z; t.b[i*4+3] = (bf16_t)v.w;
                }
            } else {
#pragma unroll
                for (int i = 0; i < 4; i++) t.q[i] = make_uint4(0,0,0,0);
            }
            uint4* dst = (uint4*)&As[row][half * 32];
#pragma unroll
            for (int i = 0; i < 4; i++) dst[i] = t.q[i];
        }
        {
            const int colc = tid >> 1, half = tid & 1;
            const uint4* src = (const uint4*)(w1t + (size_t)colc * GCN_NFEAT + k0 + half * 32);
            uint4* dst = (uint4*)&Bs[colc][half * 32];
#pragma unroll
            for (int i = 0; i < 4; i++) dst[i] = src[i];
        }
        __syncthreads();

#pragma unroll
        for (int ks = 0; ks < 2; ks++) {
            bf16x8 af[4], bfr[4];
#pragma unroll
            for (int i = 0; i < 4; i++)
                af[i] = *(const bf16x8*)&As[wm*64 + i*16 + lm][ks*32 + quad*8];
#pragma unroll
            for (int j = 0; j < 4; j++)
                bfr[j] = *(const bf16x8*)&Bs[wn*64 + j*16 + lm][ks*32 + quad*8];
#pragma unroll
            for (int i = 0; i < 4; i++)
#pragma unroll
                for (int j = 0; j < 4; j++)
                    acc[i][j] = __builtin_amdgcn_mfma_f32_16x16x32_bf16(
                        af[i], bfr[j], acc[i][j], 0, 0, 0);
        }
        __syncthreads();
    }

#pragma unroll
    for (int i = 0; i < 4; i++) {
#pragma unroll
        for (int reg = 0; reg < 4; reg++) {
            const int gr = r0 + wm*64 + i*16 + quad*4 + reg;
            if (gr < nrows) {
#pragma unroll
                for (int j = 0; j < 4; j++) {
                    const int gc = wn*64 + j*16 + lm;
                    out[(size_t)gr * GCN_NHID + gc] = (bf16_t)acc[i][j][reg];
                }
            }
        }
    }
}

// ---- spmm1: h_bf16[r,:] = relu( sum_e val[e]*sup1[col[e],:] + b1 ) ---------
// wave per row, quarter-gather: quarter q = lane>>4 handles edge 4k+q of each
// group; lane f = lane&15 owns features 8f..8f+7 (one dwordx4 of the row).
#define S1_FENCE(U) asm volatile("" : "+v"(U.x), "+v"(U.y), "+v"(U.z), "+v"(U.w));
#define S1_FMA(U, V)                                   \
    a0 = fmaf(V, blo(U.x), a0); a1 = fmaf(V, bhi(U.x), a1); \
    a2 = fmaf(V, blo(U.y), a2); a3 = fmaf(V, bhi(U.y), a3); \
    a4 = fmaf(V, blo(U.z), a4); a5 = fmaf(V, bhi(U.z), a5); \
    a6 = fmaf(V, blo(U.w), a6); a7 = fmaf(V, bhi(U.w), a7);

__global__ __launch_bounds__(256) void k_spmm1(
    const int* __restrict__ row_ptr, const int* __restrict__ col,
    const float* __restrict__ val, const bf16_t* __restrict__ sup,
    const float* __restrict__ b1, unsigned int* __restrict__ h, int nrows)
{
    const int wid  = (blockIdx.x * blockDim.x + threadIdx.x) >> 6;
    const int lane = threadIdx.x & 63;
    if (wid >= nrows) return;
    const int q = lane >> 4;            // quarter: which edge of the group
    const int f = lane & 15;            // feature block 8f..8f+7
    const int e0 = __builtin_amdgcn_readfirstlane(row_ptr[wid]);
    const int e1 = __builtin_amdgcn_readfirstlane(row_ptr[wid + 1]);
    const int n  = e1 - e0;
    const char* supb = (const char*)sup;
    const int fo = f * 16;              // byte offset within row

    float a0=0.f,a1=0.f,a2=0.f,a3=0.f,a4=0.f,a5=0.f,a6=0.f,a7=0.f;

    int base = 0;
    // main: 16-edge chunks, 4 dwordx4 gathers in flight
    for (; base + 16 <= n; base += 16) {
        const int i0 = e0 + base + q;
        const int   c0 = col[i0];      const float v0 = val[i0];
        const int   c1 = col[i0 + 4];  const float v1 = val[i0 + 4];
        const int   c2 = col[i0 + 8];  const float v2 = val[i0 + 8];
        const int   c3 = col[i0 + 12]; const float v3 = val[i0 + 12];
        uint4 u0 = *(const uint4*)(supb + (((size_t)(unsigned)c0) << 8) + fo);
        uint4 u1 = *(const uint4*)(supb + (((size_t)(unsigned)c1) << 8) + fo);
        uint4 u2 = *(const uint4*)(supb + (((size_t)(unsigned)c2) << 8) + fo);
        uint4 u3 = *(const uint4*)(supb + (((size_t)(unsigned)c3) << 8) + fo);
        S1_FENCE(u0) S1_FMA(u0, v0)
        S1_FENCE(u1) S1_FMA(u1, v1)
        S1_FENCE(u2) S1_FMA(u2, v2)
        S1_FENCE(u3) S1_FMA(u3, v3)
    }
    // tail: up to 15 edges as 1-4 guarded groups (all issued before consume)
    const int rem = n - base;
    if (rem > 0) {
        const int elast = e1 - 1;
        uint4 t0, t1, t2, t3;
        float w0 = 0.f, w1 = 0.f, w2 = 0.f, w3 = 0.f;
        {
            int gi = e0 + base + q; if (gi > elast) gi = elast;
            const int c = col[gi]; w0 = (q < rem) ? val[gi] : 0.f;
            t0 = *(const uint4*)(supb + (((size_t)(unsigned)c) << 8) + fo);
        }
        if (rem > 4) {
            int gi = e0 + base + 4 + q; if (gi > elast) gi = elast;
            const int c = col[gi]; w1 = (4 + q < rem) ? val[gi] : 0.f;
            t1 = *(const uint4*)(supb + (((size_t)(unsigned)c) << 8) + fo);
        }
        if (rem > 8) {
            int gi = e0 + base + 8 + q; if (gi > elast) gi = elast;
            const int c = col[gi]; w2 = (8 + q < rem) ? val[gi] : 0.f;
            t2 = *(const uint4*)(supb + (((size_t)(unsigned)c) << 8) + fo);
        }
        if (rem > 12) {
            int gi = e0 + base + 12 + q; if (gi > elast) gi = elast;
            const int c = col[gi]; w3 = (12 + q < rem) ? val[gi] : 0.f;
            t3 = *(const uint4*)(supb + (((size_t)(unsigned)c) << 8) + fo);
        }
        { S1_FENCE(t0) S1_FMA(t0, w0) }
        if (rem > 4)  { S1_FENCE(t1) S1_FMA(t1, w1) }
        if (rem > 8)  { S1_FENCE(t2) S1_FMA(t2, w2) }
        if (rem > 12) { S1_FENCE(t3) S1_FMA(t3, w3) }
    }

    // fold the 4 quarters (f preserved by xor 16/32)
    a0 += __shfl_xor(a0, 16, 64); a1 += __shfl_xor(a1, 16, 64);
    a2 += __shfl_xor(a2, 16, 64); a3 += __shfl_xor(a3, 16, 64);
    a4 += __shfl_xor(a4, 16, 64); a5 += __shfl_xor(a5, 16, 64);
    a6 += __shfl_xor(a6, 16, 64); a7 += __shfl_xor(a7, 16, 64);
    a0 += __shfl_xor(a0, 32, 64); a1 += __shfl_xor(a1, 32, 64);
    a2 += __shfl_xor(a2, 32, 64); a3 += __shfl_xor(a3, 32, 64);
    a4 += __shfl_xor(a4, 32, 64); a5 += __shfl_xor(a5, 32, 64);
    a6 += __shfl_xor(a6, 32, 64); a7 += __shfl_xor(a7, 32, 64);

    if (q == 0) {
        const float4 ba = *(const float4*)(b1 + f * 8);
        const float4 bc = *(const float4*)(b1 + f * 8 + 4);
        const float o0 = fmaxf(a0 + ba.x, 0.f), o1 = fmaxf(a1 + ba.y, 0.f);
        const float o2 = fmaxf(a2 + ba.z, 0.f), o3 = fmaxf(a3 + ba.w, 0.f);
        const float o4 = fmaxf(a4 + bc.x, 0.f), o5 = fmaxf(a5 + bc.y, 0.f);
        const float o6 = fmaxf(a6 + bc.z, 0.f), o7 = fmaxf(a7 + bc.w, 0.f);
        uint4 pk;
        pk.x = (unsigned)f2b(o0) | ((unsigned)f2b(o1) << 16);
        pk.y = (unsigned)f2b(o2) | ((unsigned)f2b(o3) << 16);
        pk.z = (unsigned)f2b(o4) | ((unsigned)f2b(o5) << 16);
        pk.w = (unsigned)f2b(o6) | ((unsigned)f2b(o7) << 16);
        *(uint4*)(h + ((unsigned)wid << 6) + (f << 2)) = pk;
    }
}

// ---- GEMM2 (MFMA): sup2_bf16[N,40] = bf16( h[N,128] @ W2 ) -----------------
__global__ __launch_bounds__(256) void k_gemm2(
    const bf16_t* __restrict__ h, const bf16_t* __restrict__ w2t,
    bf16_t* __restrict__ out, int nrows)
{
    __shared__ __align__(16) bf16_t As[128][136];  // [row][k]
    __shared__ __align__(16) bf16_t Bs[48][136];   // [col][k]

    const int tid  = threadIdx.x;
    const int wave = tid >> 6, lane = tid & 63;
    const int lm = lane & 15, quad = lane >> 4;
    const int r0 = blockIdx.x * 128;

    {
        const int row = tid >> 1, half = tid & 1;
        const int gr = r0 + row;
        uint4* dst = (uint4*)&As[row][half * 64];
        if (gr < nrows) {
            const uint4* src = (const uint4*)(h + (size_t)gr * GCN_NHID + half * 64);
#pragma unroll
            for (int i = 0; i < 8; i++) dst[i] = src[i];
        } else {
#pragma unroll
            for (int i = 0; i < 8; i++) dst[i] = make_uint4(0,0,0,0);
        }
    }
    // stage B: 48 rows x 16 uint4 (full 256 B row)
    for (int idx = tid; idx < 48 * 16; idx += 256) {
        const int c = idx >> 4, seg = idx & 15;
        ((uint4*)&Bs[c][0])[seg] = ((const uint4*)(w2t + (size_t)c * GCN_NHID))[seg];
    }
    __syncthreads();

    f32x4 acc[2][3] = {};
#pragma unroll
    for (int ks = 0; ks < 4; ks++) {
        bf16x8 af[2], bfr[3];
#pragma unroll
        for (int i = 0; i < 2; i++)
            af[i] = *(const bf16x8*)&As[wave*32 + i*16 + lm][ks*32 + quad*8];
#pragma unroll
        for (int j = 0; j < 3; j++)
            bfr[j] = *(const bf16x8*)&Bs[j*16 + lm][ks*32 + quad*8];
#pragma unroll
        for (int i = 0; i < 2; i++)
#pragma unroll
            for (int j = 0; j < 3; j++)
                acc[i][j] = __builtin_amdgcn_mfma_f32_16x16x32_bf16(
                    af[i], bfr[j], acc[i][j], 0, 0, 0);
    }

#pragma unroll
    for (int i = 0; i < 2; i++) {
#pragma unroll
        for (int reg = 0; reg < 4; reg++) {
            const int gr = r0 + wave*32 + i*16 + quad*4 + reg;
            if (gr < nrows) {
#pragma unroll
                for (int j = 0; j < 3; j++) {
                    const int gc = j*16 + lm;
                    if (gc < GCN_NCLASS)
                        out[(size_t)gr * GCN_NCLASS + gc] = (bf16_t)acc[i][j][reg];
                }
            }
        }
    }
}

// ---- spmm2 + bias + log_softmax -> out[N,40] fp32 --------------------------
// 3 rows per wave: group g = lane/20 handles row wid*3+g, li = lane%20 owns
// classes {2li, 2li+1} packed in one uint. 8-edge unroll (24 gathers in
// flight per wave). Tight 80 B sup2 rows. Plain loads (no NT).
__global__ __launch_bounds__(256) void k_spmm2_lsm(
    const int* __restrict__ row_ptr, const int* __restrict__ col,
    const float* __restrict__ val, const unsigned int* __restrict__ sup2,
    const float* __restrict__ b2, float* __restrict__ out, int nrows)
{
    const int wid  = (blockIdx.x * blockDim.x + threadIdx.x) >> 6;
    const int lane = threadIdx.x & 63;
    const int g    = lane / 20;            // 0..2 valid, 3 = idle lanes 60-63
    const int li   = lane - g * 20;
    const int r    = wid * 3 + g;
    const bool active = (g < 3) && (r < nrows);

    int e0 = 0, e1 = 0;
    if (active) { e0 = row_ptr[r]; e1 = row_ptr[r + 1]; }

    float ax = 0.f, ay = 0.f;
    int e = e0;
    for (; e + 7 < e1; e += 8) {
        const int c0 = col[e],   c1 = col[e+1], c2 = col[e+2], c3 = col[e+3];
        const int c4 = col[e+4], c5 = col[e+5], c6 = col[e+6], c7 = col[e+7];
        const float v0 = val[e],   v1 = val[e+1], v2 = val[e+2], v3 = val[e+3];
        const float v4 = val[e+4], v5 = val[e+5], v6 = val[e+6], v7 = val[e+7];
        const unsigned int u0 = sup2[(unsigned)(c0 * 20) + li];
        const unsigned int u1 = sup2[(unsigned)(c1 * 20) + li];
        const unsigned int u2 = sup2[(unsigned)(c2 * 20) + li];
        const unsigned int u3 = sup2[(unsigned)(c3 * 20) + li];
        const unsigned int u4 = sup2[(unsigned)(c4 * 20) + li];
        const unsigned int u5 = sup2[(unsigned)(c5 * 20) + li];
        const unsigned int u6 = sup2[(unsigned)(c6 * 20) + li];
        const unsigned int u7 = sup2[(unsigned)(c7 * 20) + li];
        ax = fmaf(v0, blo(u0), ax); ay = fmaf(v0, bhi(u0), ay);
        ax = fmaf(v1, blo(u1), ax); ay = fmaf(v1, bhi(u1), ay);
        ax = fmaf(v2, blo(u2), ax); ay = fmaf(v2, bhi(u2), ay);
        ax = fmaf(v3, blo(u3), ax); ay = fmaf(v3, bhi(u3), ay);
        ax = fmaf(v4, blo(u4), ax); ay = fmaf(v4, bhi(u4), ay);
        ax = fmaf(v5, blo(u5), ax); ay = fmaf(v5, bhi(u5), ay);
        ax = fmaf(v6, blo(u6), ax); ay = fmaf(v6, bhi(u6), ay);
        ax = fmaf(v7, blo(u7), ax); ay = fmaf(v7, bhi(u7), ay);
    }
    for (; e + 3 < e1; e += 4) {
        const int c0 = col[e],   c1 = col[e+1], c2 = col[e+2], c3 = col[e+3];
        const float v0 = val[e], v1 = val[e+1], v2 = val[e+2], v3 = val[e+3];
        const unsigned int u0 = sup2[(unsigned)(c0 * 20) + li];
        const unsigned int u1 = sup2[(unsigned)(c1 * 20) + li];
        const unsigned int u2 = sup2[(unsigned)(c2 * 20) + li];
        const unsigned int u3 = sup2[(unsigned)(c3 * 20) + li];
        ax = fmaf(v0, blo(u0), ax); ay = fmaf(v0, bhi(u0), ay);
        ax = fmaf(v1, blo(u1), ax); ay = fmaf(v1, bhi(u1), ay);
        ax = fmaf(v2, blo(u2), ax); ay = fmaf(v2, bhi(u2), ay);
        ax = fmaf(v3, blo(u3), ax); ay = fmaf(v3, bhi(u3), ay);
    }
    for (; e < e1; e++) {
        const unsigned int u = sup2[(unsigned)(col[e] * 20) + li];
        const float v = val[e];
        ax = fmaf(v, blo(u), ax); ay = fmaf(v, bhi(u), ay);
    }

    float l0 = -INFINITY, l1 = -INFINITY;
    if (active) {
        l0 = ax + b2[li * 2];
        l1 = ay + b2[li * 2 + 1];
    }

    // group-local (20-lane) shuffle reductions
    float m = fmaxf(l0, l1);
#pragma unroll
    for (int off = 16; off >= 1; off >>= 1) {
        const float t = __shfl_down(m, off, 64);
        if (li + off < 20) m = fmaxf(m, t);
    }
    m = __shfl(m, g * 20, 64);   // broadcast group max

    float s = active ? (__expf(l0 - m) + __expf(l1 - m)) : 0.f;
#pragma unroll
    for (int off = 16; off >= 1; off >>= 1) {
        const float t = __shfl_down(s, off, 64);
        if (li + off < 20) s += t;
    }
    s = __shfl(s, g * 20, 64);

    if (active) {
        const float lse = m + __logf(s);
        float* p = out + (size_t)r * GCN_NCLASS + li * 2;
        p[0] = l0 - lse;
        p[1] = l1 - lse;
    }
}

// ---------------------------------------------------------------------------
extern "C" void kernel_launch(void* const* d_in, const int* in_sizes, int n_in,
                              void* d_out, int out_size, void* d_ws, size_t ws_size,
                              hipStream_t stream)
{
    const float* x       = (const float*)d_in[0];
    const int*   adj_row = (const int*)  d_in[1];
    const int*   adj_col = (const int*)  d_in[2];
    const float* adj_val = (const float*)d_in[3];
    // d_in[4] = i (unused)
    const float* W1 = (const float*)d_in[5];
    const float* b1 = (const float*)d_in[6];
    const float* W2 = (const float*)d_in[7];
    const float* b2 = (const float*)d_in[8];
    float* out = (float*)d_out;

    const int N = in_sizes[0] / GCN_NFEAT;   // 100000
    const int E = in_sizes[1];               // 3200000

    // workspace layout (1 KiB aligned chunks)
    char* ws = (char*)d_ws;
    size_t off = 0;
    int* row_ptr = (int*)(ws + off);
    off += (((size_t)(N + 1) * sizeof(int)) + 1023) & ~(size_t)1023;
    bf16_t* w1t = (bf16_t*)(ws + off);                 // 128*256 bf16
    off += ((size_t)GCN_NHID * GCN_NFEAT * 2 + 1023) & ~(size_t)1023;
    bf16_t* w2t = (bf16_t*)(ws + off);                 // 48*128 bf16
    off += ((size_t)48 * GCN_NHID * 2 + 1023) & ~(size_t)1023;
    bf16_t* sup1 = (bf16_t*)(ws + off);                // N*128 bf16
    off += ((size_t)N * GCN_NHID * 2 + 1023) & ~(size_t)1023;
    bf16_t* h = (bf16_t*)(ws + off);                   // N*128 bf16
    bf16_t* sup2 = sup1;                               // reuse sup1 (N*40 bf16)

    const int rb = (N + 1 + 255) / 256;                // row_ptr blocks
    k_prep<<<rb + 128 + 24, 256, 0, stream>>>(adj_row, row_ptr, W1, w1t, W2, w2t,
                                              N, E, rb);
    k_gemm1<<<(N + 127) / 128, 256, 0, stream>>>(x, w1t, sup1, N);
    k_spmm1<<<(N + 3) / 4, 256, 0, stream>>>(row_ptr, adj_col, adj_val,
                                             sup1, b1, (unsigned int*)h, N);
    k_gemm2<<<(N + 127) / 128, 256, 0, stream>>>(h, w2t, sup2, N);
    const int nw2 = (N + 2) / 3;                       // waves for spmm2
    k_spmm2_lsm<<<(nw2 + 3) / 4, 256, 0, stream>>>(row_ptr, adj_col, adj_val,
                                                   (const unsigned int*)sup2, b2, out, N);
}

// Round 8
// 376.467 us; speedup vs baseline: 1.4053x; 1.0154x over previous
//
#include <hip/hip_runtime.h>
#include <hip/hip_bf16.h>
#include <math.h>

// ---------------------------------------------------------------------------
// GCN forward: out = log_softmax( A@( relu(A@(x@W1)+b1) @ W2 ) + b2 )
// Round 12: R11 config (382.3 us, best) + ONE isolated change: sup2 rows
// padded 80 B -> 128 B (stride only; pad bytes never written/read). Theory:
// spmm2's random row gather touched 1.62 L2 lines/edge at 80 B stride; at
// 128 B aligned it touches exactly 1. Fill-path bytes/edge ~93 -> ~70 even
// after the 8->12.8 MB footprint hit-rate loss. Everything else identical.
// Measured laws: spmm1 = FETCH/3.42 GB/us (fill-bound, 3 structures same);
// no NT hints (R10 +20MB fetch); no low-occupancy fusion (R9 2x regression).
// ---------------------------------------------------------------------------

#define GCN_NFEAT 256
#define GCN_NHID  128
#define GCN_NCLASS 40
#define SUP2_LD   64          // sup2 row stride in bf16 elems = 128 B

typedef __bf16 bf16_t;
typedef bf16_t bf16x8 __attribute__((ext_vector_type(8)));
typedef float  f32x4  __attribute__((ext_vector_type(4)));

static __device__ __forceinline__ unsigned short f2b(float f) {
    bf16_t b = (bf16_t)f;
    return *(unsigned short*)&b;
}
static __device__ __forceinline__ float blo(unsigned int u) {
    return __uint_as_float(u << 16);
}
static __device__ __forceinline__ float bhi(unsigned int u) {
    return __uint_as_float(u & 0xffff0000u);
}

// ---- merged prep: row_ptr + W1t + W2t in one dispatch ----------------------
__global__ __launch_bounds__(256) void k_prep(
    const int* __restrict__ row, int* __restrict__ row_ptr,
    const float* __restrict__ w1, bf16_t* __restrict__ w1t,
    const float* __restrict__ w2, bf16_t* __restrict__ w2t,
    int n_rows, int n_edges, int rb)
{
    const int b = blockIdx.x;
    if (b < rb) {
        // row_ptr[r] = lower_bound(adj_row, r)
        int r = b * 256 + threadIdx.x;
        if (r > n_rows) return;
        int lo = 0, hi = n_edges;
        while (lo < hi) {
            int mid = (lo + hi) >> 1;
            if (row[mid] < r) lo = mid + 1; else hi = mid;
        }
        row_ptr[r] = lo;
    } else if (b < rb + 128) {
        // W1t[128][256]
        int idx = (b - rb) * 256 + threadIdx.x;   // 32768 total
        int c = idx & 127;
        int k = idx >> 7;
        w1t[(size_t)c * GCN_NFEAT + k] = (bf16_t)w1[(size_t)k * GCN_NHID + c];
    } else {
        // W2t[48][128], cols 40..47 zero
        int idx = (b - rb - 128) * 256 + threadIdx.x;  // 6144 total
        if (idx >= 48 * GCN_NHID) return;
        int c = idx / GCN_NHID;
        int k = idx - c * GCN_NHID;
        float v = (c < GCN_NCLASS) ? w2[(size_t)k * GCN_NCLASS + c] : 0.f;
        w2t[idx] = (bf16_t)v;
    }
}

// ---- GEMM1 (MFMA): sup1_bf16[N,128] = bf16( x[N,256] @ W1 ) ----------------
__global__ __launch_bounds__(256) void k_gemm1(
    const float* __restrict__ x, const bf16_t* __restrict__ w1t,
    bf16_t* __restrict__ out, int nrows)
{
    __shared__ __align__(16) bf16_t As[128][72];   // [row][k]
    __shared__ __align__(16) bf16_t Bs[128][72];   // [col][k]

    const int tid  = threadIdx.x;
    const int wave = tid >> 6, lane = tid & 63;
    const int wm = wave >> 1, wn = wave & 1;
    const int lm = lane & 15, quad = lane >> 4;
    const int r0 = blockIdx.x * 128;

    f32x4 acc[4][4] = {};

    for (int k0 = 0; k0 < GCN_NFEAT; k0 += 64) {
        {
            const int row = tid >> 1, half = tid & 1;
            const int gr = r0 + row;
            union { bf16_t b[32]; uint4 q[4]; } t;
            if (gr < nrows) {
                const float* p = x + (size_t)gr * GCN_NFEAT + k0 + half * 32;
#pragma unroll
                for (int i = 0; i < 8; i++) {
                    float4 v = ((const float4*)p)[i];
                    t.b[i*4+0] = (bf16_t)v.x; t.b[i*4+1] = (bf16_t)v.y;
                    t.b[i*4+2] = (bf16_t)v.z; t.b[i*4+3] = (bf16_t)v.w;
                }
            } else {
#pragma unroll
                for (int i = 0; i < 4; i++) t.q[i] = make_uint4(0,0,0,0);
            }
            uint4* dst = (uint4*)&As[row][half * 32];
#pragma unroll
            for (int i = 0; i < 4; i++) dst[i] = t.q[i];
        }
        {
            const int colc = tid >> 1, half = tid & 1;
            const uint4* src = (const uint4*)(w1t + (size_t)colc * GCN_NFEAT + k0 + half * 32);
            uint4* dst = (uint4*)&Bs[colc][half * 32];
#pragma unroll
            for (int i = 0; i < 4; i++) dst[i] = src[i];
        }
        __syncthreads();

#pragma unroll
        for (int ks = 0; ks < 2; ks++) {
            bf16x8 af[4], bfr[4];
#pragma unroll
            for (int i = 0; i < 4; i++)
                af[i] = *(const bf16x8*)&As[wm*64 + i*16 + lm][ks*32 + quad*8];
#pragma unroll
            for (int j = 0; j < 4; j++)
                bfr[j] = *(const bf16x8*)&Bs[wn*64 + j*16 + lm][ks*32 + quad*8];
#pragma unroll
            for (int i = 0; i < 4; i++)
#pragma unroll
                for (int j = 0; j < 4; j++)
                    acc[i][j] = __builtin_amdgcn_mfma_f32_16x16x32_bf16(
                        af[i], bfr[j], acc[i][j], 0, 0, 0);
        }
        __syncthreads();
    }

#pragma unroll
    for (int i = 0; i < 4; i++) {
#pragma unroll
        for (int reg = 0; reg < 4; reg++) {
            const int gr = r0 + wm*64 + i*16 + quad*4 + reg;
            if (gr < nrows) {
#pragma unroll
                for (int j = 0; j < 4; j++) {
                    const int gc = wn*64 + j*16 + lm;
                    out[(size_t)gr * GCN_NHID + gc] = (bf16_t)acc[i][j][reg];
                }
            }
        }
    }
}

// ---- spmm1: h_bf16[r,:] = relu( sum_e val[e]*sup1[col[e],:] + b1 ) ---------
// wave per row, quarter-gather: quarter q = lane>>4 handles edge 4k+q of each
// group; lane f = lane&15 owns features 8f..8f+7 (one dwordx4 of the row).
#define S1_FENCE(U) asm volatile("" : "+v"(U.x), "+v"(U.y), "+v"(U.z), "+v"(U.w));
#define S1_FMA(U, V)                                   \
    a0 = fmaf(V, blo(U.x), a0); a1 = fmaf(V, bhi(U.x), a1); \
    a2 = fmaf(V, blo(U.y), a2); a3 = fmaf(V, bhi(U.y), a3); \
    a4 = fmaf(V, blo(U.z), a4); a5 = fmaf(V, bhi(U.z), a5); \
    a6 = fmaf(V, blo(U.w), a6); a7 = fmaf(V, bhi(U.w), a7);

__global__ __launch_bounds__(256) void k_spmm1(
    const int* __restrict__ row_ptr, const int* __restrict__ col,
    const float* __restrict__ val, const bf16_t* __restrict__ sup,
    const float* __restrict__ b1, unsigned int* __restrict__ h, int nrows)
{
    const int wid  = (blockIdx.x * blockDim.x + threadIdx.x) >> 6;
    const int lane = threadIdx.x & 63;
    if (wid >= nrows) return;
    const int q = lane >> 4;            // quarter: which edge of the group
    const int f = lane & 15;            // feature block 8f..8f+7
    const int e0 = __builtin_amdgcn_readfirstlane(row_ptr[wid]);
    const int e1 = __builtin_amdgcn_readfirstlane(row_ptr[wid + 1]);
    const int n  = e1 - e0;
    const char* supb = (const char*)sup;
    const int fo = f * 16;              // byte offset within row

    float a0=0.f,a1=0.f,a2=0.f,a3=0.f,a4=0.f,a5=0.f,a6=0.f,a7=0.f;

    int base = 0;
    // main: 16-edge chunks, 4 dwordx4 gathers in flight
    for (; base + 16 <= n; base += 16) {
        const int i0 = e0 + base + q;
        const int   c0 = col[i0];      const float v0 = val[i0];
        const int   c1 = col[i0 + 4];  const float v1 = val[i0 + 4];
        const int   c2 = col[i0 + 8];  const float v2 = val[i0 + 8];
        const int   c3 = col[i0 + 12]; const float v3 = val[i0 + 12];
        uint4 u0 = *(const uint4*)(supb + (((size_t)(unsigned)c0) << 8) + fo);
        uint4 u1 = *(const uint4*)(supb + (((size_t)(unsigned)c1) << 8) + fo);
        uint4 u2 = *(const uint4*)(supb + (((size_t)(unsigned)c2) << 8) + fo);
        uint4 u3 = *(const uint4*)(supb + (((size_t)(unsigned)c3) << 8) + fo);
        S1_FENCE(u0) S1_FMA(u0, v0)
        S1_FENCE(u1) S1_FMA(u1, v1)
        S1_FENCE(u2) S1_FMA(u2, v2)
        S1_FENCE(u3) S1_FMA(u3, v3)
    }
    // tail: up to 15 edges as 1-4 guarded groups (all issued before consume)
    const int rem = n - base;
    if (rem > 0) {
        const int elast = e1 - 1;
        uint4 t0, t1, t2, t3;
        float w0 = 0.f, w1 = 0.f, w2 = 0.f, w3 = 0.f;
        {
            int gi = e0 + base + q; if (gi > elast) gi = elast;
            const int c = col[gi]; w0 = (q < rem) ? val[gi] : 0.f;
            t0 = *(const uint4*)(supb + (((size_t)(unsigned)c) << 8) + fo);
        }
        if (rem > 4) {
            int gi = e0 + base + 4 + q; if (gi > elast) gi = elast;
            const int c = col[gi]; w1 = (4 + q < rem) ? val[gi] : 0.f;
            t1 = *(const uint4*)(supb + (((size_t)(unsigned)c) << 8) + fo);
        }
        if (rem > 8) {
            int gi = e0 + base + 8 + q; if (gi > elast) gi = elast;
            const int c = col[gi]; w2 = (8 + q < rem) ? val[gi] : 0.f;
            t2 = *(const uint4*)(supb + (((size_t)(unsigned)c) << 8) + fo);
        }
        if (rem > 12) {
            int gi = e0 + base + 12 + q; if (gi > elast) gi = elast;
            const int c = col[gi]; w3 = (12 + q < rem) ? val[gi] : 0.f;
            t3 = *(const uint4*)(supb + (((size_t)(unsigned)c) << 8) + fo);
        }
        { S1_FENCE(t0) S1_FMA(t0, w0) }
        if (rem > 4)  { S1_FENCE(t1) S1_FMA(t1, w1) }
        if (rem > 8)  { S1_FENCE(t2) S1_FMA(t2, w2) }
        if (rem > 12) { S1_FENCE(t3) S1_FMA(t3, w3) }
    }

    // fold the 4 quarters (f preserved by xor 16/32)
    a0 += __shfl_xor(a0, 16, 64); a1 += __shfl_xor(a1, 16, 64);
    a2 += __shfl_xor(a2, 16, 64); a3 += __shfl_xor(a3, 16, 64);
    a4 += __shfl_xor(a4, 16, 64); a5 += __shfl_xor(a5, 16, 64);
    a6 += __shfl_xor(a6, 16, 64); a7 += __shfl_xor(a7, 16, 64);
    a0 += __shfl_xor(a0, 32, 64); a1 += __shfl_xor(a1, 32, 64);
    a2 += __shfl_xor(a2, 32, 64); a3 += __shfl_xor(a3, 32, 64);
    a4 += __shfl_xor(a4, 32, 64); a5 += __shfl_xor(a5, 32, 64);
    a6 += __shfl_xor(a6, 32, 64); a7 += __shfl_xor(a7, 32, 64);

    if (q == 0) {
        const float4 ba = *(const float4*)(b1 + f * 8);
        const float4 bc = *(const float4*)(b1 + f * 8 + 4);
        const float o0 = fmaxf(a0 + ba.x, 0.f), o1 = fmaxf(a1 + ba.y, 0.f);
        const float o2 = fmaxf(a2 + ba.z, 0.f), o3 = fmaxf(a3 + ba.w, 0.f);
        const float o4 = fmaxf(a4 + bc.x, 0.f), o5 = fmaxf(a5 + bc.y, 0.f);
        const float o6 = fmaxf(a6 + bc.z, 0.f), o7 = fmaxf(a7 + bc.w, 0.f);
        uint4 pk;
        pk.x = (unsigned)f2b(o0) | ((unsigned)f2b(o1) << 16);
        pk.y = (unsigned)f2b(o2) | ((unsigned)f2b(o3) << 16);
        pk.z = (unsigned)f2b(o4) | ((unsigned)f2b(o5) << 16);
        pk.w = (unsigned)f2b(o6) | ((unsigned)f2b(o7) << 16);
        *(uint4*)(h + ((unsigned)wid << 6) + (f << 2)) = pk;
    }
}

// ---- GEMM2 (MFMA): sup2_bf16[N,64pad] = bf16( h[N,128] @ W2 ) --------------
// writes 40 real cols at 128 B row stride; pad bytes never written/read.
__global__ __launch_bounds__(256) void k_gemm2(
    const bf16_t* __restrict__ h, const bf16_t* __restrict__ w2t,
    bf16_t* __restrict__ out, int nrows)
{
    __shared__ __align__(16) bf16_t As[128][136];  // [row][k]
    __shared__ __align__(16) bf16_t Bs[48][136];   // [col][k]

    const int tid  = threadIdx.x;
    const int wave = tid >> 6, lane = tid & 63;
    const int lm = lane & 15, quad = lane >> 4;
    const int r0 = blockIdx.x * 128;

    {
        const int row = tid >> 1, half = tid & 1;
        const int gr = r0 + row;
        uint4* dst = (uint4*)&As[row][half * 64];
        if (gr < nrows) {
            const uint4* src = (const uint4*)(h + (size_t)gr * GCN_NHID + half * 64);
#pragma unroll
            for (int i = 0; i < 8; i++) dst[i] = src[i];
        } else {
#pragma unroll
            for (int i = 0; i < 8; i++) dst[i] = make_uint4(0,0,0,0);
        }
    }
    // stage B: 48 rows x 16 uint4 (full 256 B row)
    for (int idx = tid; idx < 48 * 16; idx += 256) {
        const int c = idx >> 4, seg = idx & 15;
        ((uint4*)&Bs[c][0])[seg] = ((const uint4*)(w2t + (size_t)c * GCN_NHID))[seg];
    }
    __syncthreads();

    f32x4 acc[2][3] = {};
#pragma unroll
    for (int ks = 0; ks < 4; ks++) {
        bf16x8 af[2], bfr[3];
#pragma unroll
        for (int i = 0; i < 2; i++)
            af[i] = *(const bf16x8*)&As[wave*32 + i*16 + lm][ks*32 + quad*8];
#pragma unroll
        for (int j = 0; j < 3; j++)
            bfr[j] = *(const bf16x8*)&Bs[j*16 + lm][ks*32 + quad*8];
#pragma unroll
        for (int i = 0; i < 2; i++)
#pragma unroll
            for (int j = 0; j < 3; j++)
                acc[i][j] = __builtin_amdgcn_mfma_f32_16x16x32_bf16(
                    af[i], bfr[j], acc[i][j], 0, 0, 0);
    }

#pragma unroll
    for (int i = 0; i < 2; i++) {
#pragma unroll
        for (int reg = 0; reg < 4; reg++) {
            const int gr = r0 + wave*32 + i*16 + quad*4 + reg;
            if (gr < nrows) {
#pragma unroll
                for (int j = 0; j < 3; j++) {
                    const int gc = j*16 + lm;
                    if (gc < GCN_NCLASS)
                        out[(size_t)gr * SUP2_LD + gc] = (bf16_t)acc[i][j][reg];
                }
            }
        }
    }
}

// ---- spmm2 + bias + log_softmax -> out[N,40] fp32 --------------------------
// 3 rows per wave: group g = lane/20 handles row wid*3+g, li = lane%20 owns
// classes {2li, 2li+1} packed in one uint. 8-edge unroll (24 gathers in
// flight per wave). sup2 rows at 128 B stride: each group access = 1 L2 line.
__global__ __launch_bounds__(256) void k_spmm2_lsm(
    const int* __restrict__ row_ptr, const int* __restrict__ col,
    const float* __restrict__ val, const unsigned int* __restrict__ sup2,
    const float* __restrict__ b2, float* __restrict__ out, int nrows)
{
    const int wid  = (blockIdx.x * blockDim.x + threadIdx.x) >> 6;
    const int lane = threadIdx.x & 63;
    const int g    = lane / 20;            // 0..2 valid, 3 = idle lanes 60-63
    const int li   = lane - g * 20;
    const int r    = wid * 3 + g;
    const bool active = (g < 3) && (r < nrows);

    int e0 = 0, e1 = 0;
    if (active) { e0 = row_ptr[r]; e1 = row_ptr[r + 1]; }

    float ax = 0.f, ay = 0.f;
    int e = e0;
    for (; e + 7 < e1; e += 8) {
        const int c0 = col[e],   c1 = col[e+1], c2 = col[e+2], c3 = col[e+3];
        const int c4 = col[e+4], c5 = col[e+5], c6 = col[e+6], c7 = col[e+7];
        const float v0 = val[e],   v1 = val[e+1], v2 = val[e+2], v3 = val[e+3];
        const float v4 = val[e+4], v5 = val[e+5], v6 = val[e+6], v7 = val[e+7];
        const unsigned int u0 = sup2[((unsigned)c0 << 5) + li];
        const unsigned int u1 = sup2[((unsigned)c1 << 5) + li];
        const unsigned int u2 = sup2[((unsigned)c2 << 5) + li];
        const unsigned int u3 = sup2[((unsigned)c3 << 5) + li];
        const unsigned int u4 = sup2[((unsigned)c4 << 5) + li];
        const unsigned int u5 = sup2[((unsigned)c5 << 5) + li];
        const unsigned int u6 = sup2[((unsigned)c6 << 5) + li];
        const unsigned int u7 = sup2[((unsigned)c7 << 5) + li];
        ax = fmaf(v0, blo(u0), ax); ay = fmaf(v0, bhi(u0), ay);
        ax = fmaf(v1, blo(u1), ax); ay = fmaf(v1, bhi(u1), ay);
        ax = fmaf(v2, blo(u2), ax); ay = fmaf(v2, bhi(u2), ay);
        ax = fmaf(v3, blo(u3), ax); ay = fmaf(v3, bhi(u3), ay);
        ax = fmaf(v4, blo(u4), ax); ay = fmaf(v4, bhi(u4), ay);
        ax = fmaf(v5, blo(u5), ax); ay = fmaf(v5, bhi(u5), ay);
        ax = fmaf(v6, blo(u6), ax); ay = fmaf(v6, bhi(u6), ay);
        ax = fmaf(v7, blo(u7), ax); ay = fmaf(v7, bhi(u7), ay);
    }
    for (; e + 3 < e1; e += 4) {
        const int c0 = col[e],   c1 = col[e+1], c2 = col[e+2], c3 = col[e+3];
        const float v0 = val[e], v1 = val[e+1], v2 = val[e+2], v3 = val[e+3];
        const unsigned int u0 = sup2[((unsigned)c0 << 5) + li];
        const unsigned int u1 = sup2[((unsigned)c1 << 5) + li];
        const unsigned int u2 = sup2[((unsigned)c2 << 5) + li];
        const unsigned int u3 = sup2[((unsigned)c3 << 5) + li];
        ax = fmaf(v0, blo(u0), ax); ay = fmaf(v0, bhi(u0), ay);
        ax = fmaf(v1, blo(u1), ax); ay = fmaf(v1, bhi(u1), ay);
        ax = fmaf(v2, blo(u2), ax); ay = fmaf(v2, bhi(u2), ay);
        ax = fmaf(v3, blo(u3), ax); ay = fmaf(v3, bhi(u3), ay);
    }
    for (; e < e1; e++) {
        const unsigned int u = sup2[((unsigned)col[e] << 5) + li];
        const float v = val[e];
        ax = fmaf(v, blo(u), ax); ay = fmaf(v, bhi(u), ay);
    }

    float l0 = -INFINITY, l1 = -INFINITY;
    if (active) {
        l0 = ax + b2[li * 2];
        l1 = ay + b2[li * 2 + 1];
    }

    // group-local (20-lane) shuffle reductions
    float m = fmaxf(l0, l1);
#pragma unroll
    for (int off = 16; off >= 1; off >>= 1) {
        const float t = __shfl_down(m, off, 64);
        if (li + off < 20) m = fmaxf(m, t);
    }
    m = __shfl(m, g * 20, 64);   // broadcast group max

    float s = active ? (__expf(l0 - m) + __expf(l1 - m)) : 0.f;
#pragma unroll
    for (int off = 16; off >= 1; off >>= 1) {
        const float t = __shfl_down(s, off, 64);
        if (li + off < 20) s += t;
    }
    s = __shfl(s, g * 20, 64);

    if (active) {
        const float lse = m + __logf(s);
        float* p = out + (size_t)r * GCN_NCLASS + li * 2;
        p[0] = l0 - lse;
        p[1] = l1 - lse;
    }
}

// ---------------------------------------------------------------------------
extern "C" void kernel_launch(void* const* d_in, const int* in_sizes, int n_in,
                              void* d_out, int out_size, void* d_ws, size_t ws_size,
                              hipStream_t stream)
{
    const float* x       = (const float*)d_in[0];
    const int*   adj_row = (const int*)  d_in[1];
    const int*   adj_col = (const int*)  d_in[2];
    const float* adj_val = (const float*)d_in[3];
    // d_in[4] = i (unused)
    const float* W1 = (const float*)d_in[5];
    const float* b1 = (const float*)d_in[6];
    const float* W2 = (const float*)d_in[7];
    const float* b2 = (const float*)d_in[8];
    float* out = (float*)d_out;

    const int N = in_sizes[0] / GCN_NFEAT;   // 100000
    const int E = in_sizes[1];               // 3200000

    // workspace layout (1 KiB aligned chunks)
    char* ws = (char*)d_ws;
    size_t off = 0;
    int* row_ptr = (int*)(ws + off);
    off += (((size_t)(N + 1) * sizeof(int)) + 1023) & ~(size_t)1023;
    bf16_t* w1t = (bf16_t*)(ws + off);                 // 128*256 bf16
    off += ((size_t)GCN_NHID * GCN_NFEAT * 2 + 1023) & ~(size_t)1023;
    bf16_t* w2t = (bf16_t*)(ws + off);                 // 48*128 bf16
    off += ((size_t)48 * GCN_NHID * 2 + 1023) & ~(size_t)1023;
    bf16_t* sup1 = (bf16_t*)(ws + off);                // N*128 bf16
    off += ((size_t)N * GCN_NHID * 2 + 1023) & ~(size_t)1023;
    bf16_t* h = (bf16_t*)(ws + off);                   // N*128 bf16
    bf16_t* sup2 = sup1;                               // reuse sup1 (N*64 bf16 padded <= N*128)

    const int rb = (N + 1 + 255) / 256;                // row_ptr blocks
    k_prep<<<rb + 128 + 24, 256, 0, stream>>>(adj_row, row_ptr, W1, w1t, W2, w2t,
                                              N, E, rb);
    k_gemm1<<<(N + 127) / 128, 256, 0, stream>>>(x, w1t, sup1, N);
    k_spmm1<<<(N + 3) / 4, 256, 0, stream>>>(row_ptr, adj_col, adj_val,
                                             sup1, b1, (unsigned int*)h, N);
    k_gemm2<<<(N + 127) / 128, 256, 0, stream>>>(h, w2t, sup2, N);
    const int nw2 = (N + 2) / 3;                       // waves for spmm2
    k_spmm2_lsm<<<(nw2 + 3) / 4, 256, 0, stream>>>(row_ptr, adj_col, adj_val,
                                                   (const unsigned int*)sup2, b2, out, N);
}